// Round 13
// baseline (96.367 us; speedup 1.0000x reference)
//
#include <hip/hip_runtime.h>

#define CLAMP_MIN_F (-10.0f)
#define CLAMP_MAX_F (10.0f)
#define BATCH 8
#define SUP_LOG 8        // 256 nodes per super-bucket
#define SNODES 256
#define MAXS 512         // max supers (N <= 131072)
#define ESTR 9           // LDS row stride (pad 8 -> 9)
#define EPB 16384        // edges per binning block
#define CH 2048          // records per LDS chunk
#define TB_BIN 1024
#define MAX4K 4096

// ---- prep: transpose o_pre (B,N) -> (N,B); zero super totals ---------------
__global__ void prep_o_kernel(const float* __restrict__ o_pre,
                              float* __restrict__ o_preT,
                              unsigned* __restrict__ total,
                              int N) {
    int n = blockIdx.x * blockDim.x + threadIdx.x;
    if (n < MAX4K) total[n] = 0u;
    if (n >= N) return;
    float o[BATCH];
    #pragma unroll
    for (int b = 0; b < BATCH; ++b) o[b] = o_pre[b * N + n];
    float4* op = (float4*)&o_preT[(size_t)n * BATCH];
    op[0] = make_float4(o[0], o[1], o[2], o[3]);
    op[1] = make_float4(o[4], o[5], o[6], o[7]);
}

// ---- pass 1: per-block super histogram + space reservation -----------------
__global__ __launch_bounds__(TB_BIN)
void hist_reserve_kernel(const int* __restrict__ dst,
                         unsigned* __restrict__ superTotal,
                         unsigned* __restrict__ offs0s,
                         int edges) {
    __shared__ unsigned sh[MAXS];
    int bid = blockIdx.x, tid = threadIdx.x;
    for (int s = tid; s < MAXS; s += blockDim.x) sh[s] = 0u;
    __syncthreads();
    int start = bid * EPB;
    int endE = min(edges, start + EPB);
    for (int i = start + tid; i < endE; i += blockDim.x)
        atomicAdd(&sh[((unsigned)dst[i]) >> SUP_LOG], 1u);
    __syncthreads();
    for (int s = tid; s < MAXS; s += blockDim.x) {
        unsigned c = sh[s];
        offs0s[(size_t)bid * MAXS + s] = c ? atomicAdd(&superTotal[s], c) : 0u;
    }
}

// ---- pass 2: exclusive scan over super totals (uses 4096-wide machinery) ---
__global__ void scan4_kernel(const unsigned* __restrict__ total,
                             unsigned* __restrict__ base,
                             int KPAD) {
    __shared__ unsigned s1[1024];
    __shared__ unsigned s2[1024];
    int t = threadIdx.x;
    unsigned v0 = (4 * t     < KPAD) ? total[4 * t]     : 0u;
    unsigned v1 = (4 * t + 1 < KPAD) ? total[4 * t + 1] : 0u;
    unsigned v2 = (4 * t + 2 < KPAD) ? total[4 * t + 2] : 0u;
    unsigned v3 = (4 * t + 3 < KPAD) ? total[4 * t + 3] : 0u;
    unsigned sum = v0 + v1 + v2 + v3;
    s1[t] = sum;
    __syncthreads();
    unsigned* cur = s1;
    unsigned* nxt = s2;
    for (int off = 1; off < 1024; off <<= 1) {
        unsigned x = cur[t];
        if (t >= off) x += cur[t - off];
        __syncthreads();
        nxt[t] = x;
        __syncthreads();
        unsigned* tmp = cur; cur = nxt; nxt = tmp;
    }
    unsigned incl = cur[t];
    unsigned excl = incl - sum;
    base[4 * t]     = excl;
    base[4 * t + 1] = excl + v0;
    base[4 * t + 2] = excl + v0 + v1;
    base[4 * t + 3] = excl + v0 + v1 + v2;
    if (t == 1023) base[MAX4K] = incl;
}

// ---- pass 3: LDS-staged scatter into super-sorted records (coalesced) ------
// Per 2048-edge chunk: counting-sort by super in LDS, then copy out sorted
// runs with consecutive threads -> coalesced stores. Per-block cursor lines
// = NS*64B ~ 25KB -> stays L2-resident -> full-line writebacks.
// key = (dst & 255) << 17 | src   (src < 2^17)
__global__ __launch_bounds__(TB_BIN)
void scatter_kernel(const int* __restrict__ src,
                    const int* __restrict__ dst,
                    const float* __restrict__ w,
                    const unsigned* __restrict__ offs0s,
                    const unsigned* __restrict__ baseS,
                    int2* __restrict__ recS,
                    int edges) {
    __shared__ int2 srec[CH];
    __shared__ unsigned short ssup[CH];
    __shared__ unsigned cnt[MAXS];
    __shared__ unsigned sstart[MAXS];
    __shared__ unsigned cursor[MAXS];
    __shared__ unsigned pa[MAXS];
    __shared__ unsigned pb[MAXS];
    int bid = blockIdx.x, tid = threadIdx.x;
    for (int s = tid; s < MAXS; s += blockDim.x)
        cursor[s] = baseS[s] + offs0s[(size_t)bid * MAXS + s];
    int start = bid * EPB;
    int endE = min(edges, start + EPB);
    for (int cs = start; cs < endE; cs += CH) {
        int m = min(CH, endE - cs);
        __syncthreads();
        for (int s = tid; s < MAXS; s += blockDim.x) cnt[s] = 0u;
        __syncthreads();
        int2 hrec[2]; unsigned hsup[2], hpos[2]; bool hv[2];
        #pragma unroll
        for (int j = 0; j < 2; ++j) {
            int i = tid + j * TB_BIN;
            hv[j] = (i < m);
            if (hv[j]) {
                int gi = cs + i;
                int d = dst[gi];
                unsigned key = (((unsigned)d & (SNODES - 1)) << 17) | (unsigned)src[gi];
                hrec[j] = make_int2((int)key, __float_as_int(w[gi]));
                hsup[j] = (unsigned)d >> SUP_LOG;
                hpos[j] = atomicAdd(&cnt[hsup[j]], 1u);
            }
        }
        __syncthreads();
        // exclusive prefix cnt -> sstart (512 wide)
        {
            unsigned* cur = pa;
            unsigned* nxt = pb;
            if (tid < MAXS) cur[tid] = cnt[tid];
            __syncthreads();
            for (int off = 1; off < MAXS; off <<= 1) {
                unsigned v = 0;
                if (tid < MAXS) { v = cur[tid]; if (tid >= off) v += cur[tid - off]; }
                __syncthreads();
                if (tid < MAXS) nxt[tid] = v;
                __syncthreads();
                unsigned* t2 = cur; cur = nxt; nxt = t2;
            }
            if (tid < MAXS) sstart[tid] = cur[tid] - cnt[tid];
            __syncthreads();
        }
        // scatter into sorted LDS array
        #pragma unroll
        for (int j = 0; j < 2; ++j) {
            if (hv[j]) {
                unsigned idx = sstart[hsup[j]] + hpos[j];
                srec[idx] = hrec[j];
                ssup[idx] = (unsigned short)hsup[j];
            }
        }
        __syncthreads();
        // coalesced copy-out of sorted runs
        #pragma unroll
        for (int j = 0; j < 2; ++j) {
            int i = tid + j * TB_BIN;
            if (i < m) {
                unsigned sup = ssup[i];
                unsigned gpos = cursor[sup] + ((unsigned)i - sstart[sup]);
                recS[gpos] = srec[i];
            }
        }
        __syncthreads();
        for (int s = tid; s < MAXS; s += blockDim.x) cursor[s] += cnt[s];
    }
}

// ---- pass 4: per-super counting-sort + register accumulate + finalize ------
// 128 groups of 8 lanes; group g owns nodes g and g+128 (register acc each).
__global__ __launch_bounds__(TB_BIN)
void accum_kernel(const int2* __restrict__ recS,
                  const unsigned* __restrict__ baseS,
                  const float* __restrict__ o_preT,   // (N,B)
                  const float* __restrict__ E,        // (B,N)
                  const float* __restrict__ chem_in,  // (B,N)
                  const float* __restrict__ thr,
                  const float* __restrict__ decay,
                  float* __restrict__ new_o,          // (B,N)
                  float* __restrict__ new_e,          // (B,N)
                  int N) {
    __shared__ int2 srec[CH];                      // 16 KB
    __shared__ float e_lds[SNODES * ESTR];         // 9 KB
    __shared__ float acc_st[SNODES * ESTR];        // 9 KB
    __shared__ unsigned cnt[SNODES];
    __shared__ unsigned sstart[SNODES];
    __shared__ unsigned pa[SNODES];
    __shared__ unsigned pb[SNODES];
    int sb = blockIdx.x;
    int ns = sb << SUP_LOG;
    int cntn = min(SNODES, N - ns);
    int tid = threadIdx.x;

    for (int i = tid; i < SNODES * BATCH; i += blockDim.x) {
        int b = i >> SUP_LOG;
        int n = i & (SNODES - 1);
        if (n < cntn) e_lds[n * ESTR + b] = E[(size_t)b * N + ns + n];
    }
    __syncthreads();

    int b = tid & 7;
    int g = tid >> 3;                 // 0..127
    float En0 = e_lds[g * ESTR + b];
    float En1 = e_lds[(g + 128) * ESTR + b];
    float acc0 = 0.f, acc1 = 0.f;

    unsigned r0 = baseS[sb], r1 = baseS[sb + 1];
    for (unsigned cs = r0; cs < r1; cs += CH) {
        unsigned m = min((unsigned)CH, r1 - cs);
        for (int s = tid; s < SNODES; s += blockDim.x) cnt[s] = 0u;
        __syncthreads();
        int2 hrec[2]; unsigned hdl[2], hpos[2]; bool hv[2];
        #pragma unroll
        for (int j = 0; j < 2; ++j) {
            unsigned i = (unsigned)tid + (unsigned)j * TB_BIN;
            hv[j] = (i < m);
            if (hv[j]) {
                int2 rec = recS[cs + i];
                unsigned dl = ((unsigned)rec.x >> 17) & (SNODES - 1);
                hrec[j] = rec;
                hdl[j] = dl;
                hpos[j] = atomicAdd(&cnt[dl], 1u);
            }
        }
        __syncthreads();
        // exclusive prefix cnt -> sstart (256 wide)
        {
            unsigned* cur = pa;
            unsigned* nxt = pb;
            if (tid < SNODES) cur[tid] = cnt[tid];
            __syncthreads();
            for (int off = 1; off < SNODES; off <<= 1) {
                unsigned v = 0;
                if (tid < SNODES) { v = cur[tid]; if (tid >= off) v += cur[tid - off]; }
                __syncthreads();
                if (tid < SNODES) nxt[tid] = v;
                __syncthreads();
                unsigned* t2 = cur; cur = nxt; nxt = t2;
            }
            if (tid < SNODES) sstart[tid] = cur[tid] - cnt[tid];
            __syncthreads();
        }
        #pragma unroll
        for (int j = 0; j < 2; ++j)
            if (hv[j]) srec[sstart[hdl[j]] + hpos[j]] = hrec[j];
        __syncthreads();
        // group g scans its two nodes' records; register accumulate
        {
            unsigned st = sstart[g], en = st + cnt[g];
            for (unsigned r = st; r < en; ++r) {
                int2 rec = srec[r];
                unsigned si = (unsigned)rec.x & 0x1FFFFu;
                float Oj = o_preT[((size_t)si << 3) + b];
                float wv = __int_as_float(rec.y);
                float df = Oj - En0;
                float sg = (df > 0.f) ? 1.f : ((df < 0.f) ? -1.f : 0.f);
                acc0 += Oj * wv * sg;
            }
        }
        {
            unsigned st = sstart[g + 128], en = st + cnt[g + 128];
            for (unsigned r = st; r < en; ++r) {
                int2 rec = srec[r];
                unsigned si = (unsigned)rec.x & 0x1FFFFu;
                float Oj = o_preT[((size_t)si << 3) + b];
                float wv = __int_as_float(rec.y);
                float df = Oj - En1;
                float sg = (df > 0.f) ? 1.f : ((df < 0.f) ? -1.f : 0.f);
                acc1 += Oj * wv * sg;
            }
        }
        __syncthreads();   // before cnt/srec reuse
    }

    acc_st[g * ESTR + b] = acc0;
    acc_st[(g + 128) * ESTR + b] = acc1;
    __syncthreads();

    // fused finalize: 256 nodes x 8 batches = 2048 elems
    for (int i = tid; i < SNODES * BATCH; i += blockDim.x) {
        int bb = i >> SUP_LOG;
        int n = i & (SNODES - 1);
        if (n >= cntn) continue;
        float e = e_lds[n * ESTR + bb];
        float S = e + chem_in[(size_t)bb * N + ns + n] + acc_st[n * ESTR + bb];
        S = fminf(fmaxf(S, CLAMP_MIN_F), CLAMP_MAX_F);
        float t  = thr[ns + n];
        float dc = decay[ns + n];
        bool gt = S > t;
        float no = fmaxf(S - t, 0.f);
        float ne = gt ? no : ((S == e) ? (e - dc) : S);
        new_o[(size_t)bb * N + ns + n] = no;
        new_e[(size_t)bb * N + ns + n] = ne;
    }
}

// ---------------- fallback: R3 atomic path ----------------------------------
__global__ void prep_kernel(const float* __restrict__ chem_in,
                            const float* __restrict__ o_pre,
                            const float* __restrict__ E,
                            float* __restrict__ chemT,
                            float* __restrict__ o_preT,
                            float* __restrict__ E_T,
                            int N) {
    int n = blockIdx.x * blockDim.x + threadIdx.x;
    if (n >= N) return;
    float c[BATCH], o[BATCH], ee[BATCH];
    #pragma unroll
    for (int b = 0; b < BATCH; ++b) {
        c[b]  = chem_in[b * N + n];
        o[b]  = o_pre[b * N + n];
        ee[b] = E[b * N + n];
    }
    float4* cp = (float4*)&chemT[(size_t)n * BATCH];
    cp[0] = make_float4(c[0], c[1], c[2], c[3]);
    cp[1] = make_float4(c[4], c[5], c[6], c[7]);
    float4* op = (float4*)&o_preT[(size_t)n * BATCH];
    op[0] = make_float4(o[0], o[1], o[2], o[3]);
    op[1] = make_float4(o[4], o[5], o[6], o[7]);
    float4* ep = (float4*)&E_T[(size_t)n * BATCH];
    ep[0] = make_float4(ee[0], ee[1], ee[2], ee[3]);
    ep[1] = make_float4(ee[4], ee[5], ee[6], ee[7]);
}
__global__ void edge_scatter_eb(const int* __restrict__ src,
                                const int* __restrict__ dst,
                                const float* __restrict__ w,
                                const float* __restrict__ o_preT,
                                const float* __restrict__ E_T,
                                float* __restrict__ chemT,
                                int edges) {
    int t = blockIdx.x * blockDim.x + threadIdx.x;
    int e = t >> 3;
    int b = t & 7;
    if (e >= edges) return;
    int s = src[e]; int d = dst[e]; float we = w[e];
    float Oj = o_preT[(size_t)s * BATCH + b];
    float En = E_T[(size_t)d * BATCH + b];
    float diff = Oj - En;
    float sg = (diff > 0.0f) ? 1.0f : ((diff < 0.0f) ? -1.0f : 0.0f);
    atomicAdd(&chemT[(size_t)d * BATCH + b], Oj * we * sg);
}
__global__ void finalize_nb(const float* __restrict__ E,
                            const float* __restrict__ chemT,
                            const float* __restrict__ thr,
                            const float* __restrict__ decay,
                            float* __restrict__ new_o,
                            float* __restrict__ new_e, int N) {
    int n = blockIdx.x * blockDim.x + threadIdx.x;
    if (n >= N) return;
    const float4* cp = (const float4*)&chemT[(size_t)n * BATCH];
    float4 c0 = cp[0], c1 = cp[1];
    float c[BATCH] = {c0.x, c0.y, c0.z, c0.w, c1.x, c1.y, c1.z, c1.w};
    float t = thr[n];
    float dc = decay[n];
    #pragma unroll
    for (int b = 0; b < BATCH; ++b) {
        int i = b * N + n;
        float e = E[i];
        float S = fminf(fmaxf(e + c[b], CLAMP_MIN_F), CLAMP_MAX_F);
        bool gt = S > t;
        float no = fmaxf(S - t, 0.0f);
        float ne = gt ? no : ((S == e) ? (e - dc) : S);
        new_o[i] = no;
        new_e[i] = ne;
    }
}

static inline size_t align256(size_t x) { return (x + 255) & ~(size_t)255; }

extern "C" void kernel_launch(void* const* d_in, const int* in_sizes, int n_in,
                              void* d_out, int out_size, void* d_ws, size_t ws_size,
                              hipStream_t stream) {
    const float* chem_influence = (const float*)d_in[0];
    const float* E              = (const float*)d_in[1];
    const int*   src            = (const int*)d_in[3];
    const int*   dst            = (const int*)d_in[4];
    const float* w              = (const float*)d_in[5];
    const float* o_pre          = (const float*)d_in[6];
    const float* threshold      = (const float*)d_in[7];
    const float* decay          = (const float*)d_in[8];

    const int edges = in_sizes[3];
    const int BN    = in_sizes[0];   // B * N
    const int N     = in_sizes[7];   // threshold is (N,)

    float* new_o = (float*)d_out;
    float* new_e = (float*)d_out + BN;

    const int TB = 256;
    int nblk = (N + TB - 1) / TB;

    const int NS = (N + SNODES - 1) >> SUP_LOG;   // super-buckets
    const int NB = (edges + EPB - 1) / EPB;       // binning blocks

    // ws layout
    size_t off = 0;
    size_t opreT_off  = off; off += align256((size_t)BN * 4);
    size_t base_off   = off; off += align256((size_t)(MAX4K + 1) * 4);
    size_t total_off  = off; off += align256((size_t)MAX4K * 4);
    size_t offs0_off  = off; off += align256((size_t)NB * MAXS * 4);
    size_t rec_off    = off; off += align256((size_t)edges * 8);
    size_t need = off;

    char* wsb = (char*)d_ws;

    if (NS <= MAXS && N <= (1 << 17) && ws_size >= need) {
        float*    o_preT = (float*)(wsb + opreT_off);
        unsigned* baseS  = (unsigned*)(wsb + base_off);
        unsigned* total  = (unsigned*)(wsb + total_off);
        unsigned* offs0s = (unsigned*)(wsb + offs0_off);
        int2*     recS   = (int2*)(wsb + rec_off);

        prep_o_kernel<<<nblk, TB, 0, stream>>>(o_pre, o_preT, total, N);
        hist_reserve_kernel<<<NB, TB_BIN, 0, stream>>>(dst, total, offs0s, edges);
        scan4_kernel<<<1, 1024, 0, stream>>>(total, baseS, MAXS);
        scatter_kernel<<<NB, TB_BIN, 0, stream>>>(src, dst, w, offs0s, baseS,
                                                  recS, edges);
        accum_kernel<<<NS, TB_BIN, 0, stream>>>(recS, baseS, o_preT, E,
                                                chem_influence, threshold, decay,
                                                new_o, new_e, N);
    } else if (ws_size >= 3 * (size_t)BN * 4) {
        float* chemT  = (float*)d_ws;
        float* o_preT = chemT + BN;
        float* E_T    = o_preT + BN;
        prep_kernel<<<nblk, TB, 0, stream>>>(chem_influence, o_pre, E,
                                             chemT, o_preT, E_T, N);
        long long ethreads = (long long)edges * BATCH;
        int gblk = (int)((ethreads + TB - 1) / TB);
        edge_scatter_eb<<<gblk, TB, 0, stream>>>(src, dst, w, o_preT, E_T,
                                                 chemT, edges);
        finalize_nb<<<nblk, TB, 0, stream>>>(E, chemT, threshold, decay,
                                             new_o, new_e, N);
    }
}